// Round 9
// baseline (14856.667 us; speedup 1.0000x reference)
//
#include <hip/hip_runtime.h>
#include <cmath>

// ---------------------------------------------------------------------------
// Graves handwriting synthesis: 3-layer GRU + attention window + MDN head
// B=32 T=512 U=64 V=60 H=400 K=10 M=20 IN=3
//
// Round 9: decoupled group barriers.
//  - 6 independent groups (3 layers x 2 batch-halves, 25 blocks each), each
//    with its own 25-arrival barrier. No global convoy.
//  - Cross-layer deps via monotonic progress counters (padded L3 lines):
//      L0 step t: wait prog1 >= t-3                (ring0 slot reuse)
//      L1 step t: wait prog0 >= t+1, prog2 >= t-3  (h0(t) ready; ring1/wring reuse)
//      L2 step t: wait prog1 >= t+1                (h1(t) + w(t) ready)
//    After each group barrier, the slice-0 block bumps its prog to t+1.
//  - FIX: wring now published by L1 (computes w(t) anyway) -> w(511) correct
//    (r7/r8 had L0 publish; L2's t=511 read stale w(508), under-threshold).
//  Math / fragments / staging identical to r8 (passed, absmax 0.031).
// ---------------------------------------------------------------------------

typedef __attribute__((ext_vector_type(8))) short bf16x8;
typedef __attribute__((ext_vector_type(4))) float f32x4;
typedef unsigned short ushort_t;

namespace {
constexpr int B_ = 32, T_ = 512, U_ = 64, V_ = 60, H_ = 400, K_ = 10, M_ = 20;
constexpr int N_ = B_ * T_;          // 16384
constexpr int SEG = 416, FEAT_LD = 1248;
constexpr int NBLK = 150;
constexpr int SBL = 872;             // B-row stride in LDS (u16), 16B-aligned

// workspace layout (float indices)
constexpr size_t OFF_R0    = 0;                       // 4*32*400 u32 per ring
constexpr size_t OFF_R1    = 51200;
constexpr size_t OFF_R2    = 102400;
constexpr size_t OFF_WRING = 153600;                  // 4*32*60 f32
constexpr size_t OFF_BAR   = 161280;                  // 1088 uints padded
constexpr size_t ZERO_TOT  = OFF_BAR + 1088;
constexpr size_t OFF_FEATH = ZERO_TOT;                // N*1248 bf16
constexpr size_t OFF_FEATL = OFF_FEATH + (size_t)N_ * FEAT_LD / 2;
constexpr size_t OFF_WHH   = OFF_FEATL + (size_t)N_ * FEAT_LD / 2;  // 128*1248 bf16
constexpr size_t OFF_WHL   = OFF_WHH + (size_t)128 * FEAT_LD / 2;
constexpr size_t OFF_P     = OFF_WHL + (size_t)128 * FEAT_LD / 2;   // N*128 f32

// bar layout (uints, relative): [128+64*gid]=gen, [+32]=cnt (6 groups);
// [640+64*pid]=progress counter, pid = L*2+half.
constexpr int BAR_GRP  = 128;
constexpr int BAR_PROG = 640;

// d_out layout (floats), reference return order
constexpr int DO_MEANS = 0;
constexpr int DO_STD   = B_ * T_ * M_ * 2;
constexpr int DO_LOGW  = DO_STD + B_ * T_ * M_;
constexpr int DO_CORR  = DO_LOGW + B_ * T_ * M_;
constexpr int DO_LAST  = DO_CORR + B_ * T_ * M_;
constexpr int DO_PHI   = DO_LAST + B_ * T_;
} // namespace

// ---------------------------------------------------------------------------
__device__ __forceinline__ float load_agent(const float* p) {
  return __hip_atomic_load(p, __ATOMIC_RELAXED, __HIP_MEMORY_SCOPE_AGENT);
}
__device__ __forceinline__ void store_agent(float* p, float v) {
  __hip_atomic_store(p, v, __ATOMIC_RELAXED, __HIP_MEMORY_SCOPE_AGENT);
}
__device__ __forceinline__ void store_agent_u32(unsigned* p, unsigned v) {
  __hip_atomic_store(p, v, __ATOMIC_RELAXED, __HIP_MEMORY_SCOPE_AGENT);
}
__device__ __forceinline__ unsigned load_agent_u32(const unsigned* p) {
  return __hip_atomic_load(p, __ATOMIC_RELAXED, __HIP_MEMORY_SCOPE_AGENT);
}
__device__ __forceinline__ unsigned long long load_agent_u64(const unsigned long long* p) {
  return __hip_atomic_load(p, __ATOMIC_RELAXED, __HIP_MEMORY_SCOPE_AGENT);
}
__device__ __forceinline__ ushort_t f2bf(float f) {
  union { float f; unsigned u; } x{f};
  unsigned r = x.u + 0x7FFFu + ((x.u >> 16) & 1u);
  return (ushort_t)(r >> 16);
}
__device__ __forceinline__ void split2(float f, ushort_t& h, ushort_t& l) {
  h = f2bf(f);
  union { unsigned u; float f; } c;
  c.u = ((unsigned)h) << 16;
  l = f2bf(f - c.f);
}
__device__ __forceinline__ float bfpair(ushort_t h, ushort_t l) {
  union { unsigned u; float f; } a, b;
  a.u = ((unsigned)h) << 16; b.u = ((unsigned)l) << 16;
  return a.f + b.f;
}
__device__ __forceinline__ float sigmoidf_(float x) {
  return 1.f / (1.f + __expf(-x));
}

// thread-0-only: spin until *p >= v (monotonic counter; v<=0 -> no wait)
__device__ __forceinline__ void wait_ge(const unsigned* p, int v) {
  if (v <= 0) return;
  while ((int)load_agent_u32(p) < v) __builtin_amdgcn_s_sleep(1);
}

// 25-block group barrier: gen at *gen, cnt at gen+32 (separate L3 lines).
__device__ __forceinline__ void group_barrier(unsigned* gen) {
  unsigned* cnt = gen + 32;
  __builtin_amdgcn_s_waitcnt(0);
  __syncthreads();
  __atomic_signal_fence(__ATOMIC_SEQ_CST);
  if (threadIdx.x == 0) {
    unsigned g = load_agent_u32(gen);
    unsigned a = __hip_atomic_fetch_add(cnt, 1u, __ATOMIC_RELAXED,
                                        __HIP_MEMORY_SCOPE_AGENT);
    if (a == 24u) {
      __hip_atomic_store(cnt, 0u, __ATOMIC_RELAXED, __HIP_MEMORY_SCOPE_AGENT);
      __builtin_amdgcn_s_waitcnt(0);   // reset lands before gen flip
      __hip_atomic_store(gen, g + 1u, __ATOMIC_RELAXED, __HIP_MEMORY_SCOPE_AGENT);
    } else {
      while (load_agent_u32(gen) == g) __builtin_amdgcn_s_sleep(1);
    }
  }
  __atomic_signal_fence(__ATOMIC_SEQ_CST);
  __syncthreads();
}

// stage one packed-ring 16x400 region into LDS split arrays (koff = col base)
__device__ __forceinline__ void stage_ring16(const unsigned* __restrict__ src,
                                             ushort_t* __restrict__ BhB,
                                             ushort_t* __restrict__ BlB, int koff) {
  for (int pi = threadIdx.x; pi < 3200; pi += 256) {   // 6400 elems / 2
    int e = pi * 2;
    int b = e / 400, k = e - b * 400;
    unsigned long long v = load_agent_u64((const unsigned long long*)(src + e));
    unsigned p0 = (unsigned)v, p1 = (unsigned)(v >> 32);
    unsigned hp = (p0 >> 16) | (p1 & 0xFFFF0000u);
    unsigned lp = (p0 & 0xFFFFu) | (p1 << 16);
    *(unsigned*)(BhB + b * SBL + koff + k) = hp;
    *(unsigned*)(BlB + b * SBL + koff + k) = lp;
  }
}

// ---------------------------------------------------------------------------
__global__ __launch_bounds__(256)
void zero_ws(float* __restrict__ p) {
  size_t i = (size_t)blockIdx.x * 256 + threadIdx.x;
  if (i < ZERO_TOT) p[i] = 0.f;
}

__global__ void zero_feat_pads(ushort_t* __restrict__ fh, ushort_t* __restrict__ fl) {
  int idx = blockIdx.x * 256 + threadIdx.x;
  if (idx >= N_ * 48) return;
  int n = idx / 48, r = idx % 48;
  size_t o = (size_t)n * FEAT_LD + (r / 16) * SEG + 400 + (r % 16);
  fh[o] = 0; fl[o] = 0;
}

__global__ void split_wh_kernel(const float* __restrict__ Wh,
                                ushort_t* __restrict__ hi, ushort_t* __restrict__ lo) {
  int idx = blockIdx.x * 256 + threadIdx.x;
  if (idx >= 128 * FEAT_LD) return;
  int m = idx / FEAT_LD, k = idx % FEAT_LD;
  int seg = k / SEG, off = k % SEG;
  float v = (m < 121 && off < 400) ? Wh[(size_t)m * 1200 + seg * 400 + off] : 0.f;
  ushort_t h, l; split2(v, h, l);
  hi[idx] = h; lo[idx] = l;
}

__global__ __launch_bounds__(256)
void gemm_split_kernel(const ushort_t* __restrict__ Ahi, const ushort_t* __restrict__ Alo,
                       const ushort_t* __restrict__ Bhi, const ushort_t* __restrict__ Blo,
                       const float* __restrict__ bias, float* __restrict__ C,
                       int mtiles, int ntiles, int ktiles, int strideA, int strideB,
                       int Mvalid, int ldc) {
  int wave = blockIdx.x * 4 + (threadIdx.x >> 6);
  if (wave >= mtiles * ntiles) return;
  int mt = wave / ntiles, nt = wave % ntiles;
  int lane = threadIdx.x & 63, l15 = lane & 15, quad = lane >> 4;
  size_t aoff = (size_t)(mt * 16 + l15) * strideA + quad * 8;
  size_t boff = (size_t)(nt * 16 + l15) * strideB + quad * 8;
  f32x4 acc = {0.f, 0.f, 0.f, 0.f};
  for (int kt = 0; kt < ktiles; ++kt) {
    bf16x8 ah = *(const bf16x8*)(Ahi + aoff + kt * 32);
    bf16x8 al = *(const bf16x8*)(Alo + aoff + kt * 32);
    bf16x8 bh = *(const bf16x8*)(Bhi + boff + kt * 32);
    bf16x8 bl = *(const bf16x8*)(Blo + boff + kt * 32);
    acc = __builtin_amdgcn_mfma_f32_16x16x32_bf16(ah, bh, acc, 0, 0, 0);
    acc = __builtin_amdgcn_mfma_f32_16x16x32_bf16(ah, bl, acc, 0, 0, 0);
    acc = __builtin_amdgcn_mfma_f32_16x16x32_bf16(al, bh, acc, 0, 0, 0);
  }
  int n = nt * 16 + l15;
#pragma unroll
  for (int r = 0; r < 4; ++r) {
    int m = mt * 16 + quad * 4 + r;
    if (m < Mvalid) C[(size_t)n * ldc + m] = acc[r] + bias[m];
  }
}

// ---------------------------------------------------------------------------
// fused pipelined scan body (templated per layer)
template <int L>
__device__ __forceinline__ void scan_body(
    int slice, int bhalf,
    const float* __restrict__ x, const int* __restrict__ c,
    const float* __restrict__ Wih, const float* __restrict__ Whh,
    const float* __restrict__ bih, const float* __restrict__ bhh,
    const float* __restrict__ Ww, const float* __restrict__ bw,
    unsigned* __restrict__ ringS, const unsigned* __restrict__ ringP,
    const float* __restrict__ wring_c, float* __restrict__ wring_w,
    ushort_t* __restrict__ fh, ushort_t* __restrict__ fl,
    float* __restrict__ out_phi, unsigned* __restrict__ bar,
    ushort_t* Bh, ushort_t* Bl, float (*su)[65], float (*sp)[33],
    float (*skap)[10], unsigned char (*sc)[64]) {
  constexpr int KT = (L == 0) ? 15 : 27;
  constexpr int CONST_K = (L == 0) ? 463 : 863;
  constexpr int XOFF = (L == 0) ? 460 : 860;
  constexpr int WOFF = (L == 0) ? 400 : 800;
  constexpr int IW = (L == 0) ? 63 : 463;
  const int tid = threadIdx.x;
  const int waveid = tid >> 6, lane = tid & 63;
  const int l15 = lane & 15, quad = lane >> 4;
  const int rt = waveid;                 // rowtile 0..3
  const int m = l15;
  const int uu = m & 3, gate = m >> 2;   // 0=r 1=z 2=hn 3=inn
  const int J = slice * 16 + rt * 4 + uu;
  const int B0 = bhalf * 16;             // first global sample of this block

  // barrier/progress plumbing
  unsigned* gen   = bar + BAR_GRP + 64 * (L * 2 + bhalf);
  unsigned* prog0 = bar + BAR_PROG + 64 * (0 * 2 + bhalf);
  unsigned* prog1 = bar + BAR_PROG + 64 * (1 * 2 + bhalf);
  unsigned* prog2 = bar + BAR_PROG + 64 * (2 * 2 + bhalf);
  unsigned* progS = bar + BAR_PROG + 64 * (L * 2 + bhalf);

  // ---- main A-fragments (split bf16), in registers for all 512 steps ----
  bf16x8 afh[KT], afl[KT];
#pragma unroll
  for (int kt = 0; kt < KT; ++kt) {
    union { bf16x8 v; ushort_t s[8]; } uh, ul;
#pragma unroll
    for (int j = 0; j < 8; ++j) {
      int k = kt * 32 + quad * 8 + j;
      float v = 0.f;
      if (k < 400) {
        if (gate == 0)      v = Whh[(size_t)J * 400 + k];
        else if (gate == 1) v = Whh[(size_t)(400 + J) * 400 + k];
        else if (gate == 2) v = Whh[(size_t)(800 + J) * 400 + k];
      } else if (k < CONST_K) {
        int col;
        if (L == 0) col = (k < 460) ? 3 + (k - 400) : (k - 460);
        else        col = (k < 800) ? 3 + (k - 400)
                        : (k < 860) ? 403 + (k - 800) : (k - 860);
        if (gate == 0)      v = Wih[(size_t)J * IW + col];
        else if (gate == 1) v = Wih[(size_t)(400 + J) * IW + col];
        else if (gate == 3) v = Wih[(size_t)(800 + J) * IW + col];
      } else if (k == CONST_K) {
        if (gate == 0)      v = bih[J] + bhh[J];
        else if (gate == 1) v = bih[400 + J] + bhh[400 + J];
        else if (gate == 2) v = bhh[800 + J];
        else                v = bih[800 + J];
      }
      ushort_t h, l; split2(v, h, l);
      uh.s[j] = h; ul.s[j] = l;
    }
    afh[kt] = uh.v; afl[kt] = ul.v;
  }

  // ---- attention p-fragments (Ww rows, split), L0/L1: waves 0/1 own 16 rows
  bf16x8 apfh[14], apfl[14];
  if constexpr (L <= 1) {
    const int prow = (waveid < 2) ? (waveid * 16 + l15) : 32;
#pragma unroll
    for (int pk = 0; pk < 14; ++pk) {
      int kt = (pk < 13) ? ((L == 0) ? pk : 12 + pk) : ((L == 0) ? 14 : 26);
      union { bf16x8 v; ushort_t s[8]; } uh, ul;
#pragma unroll
      for (int j = 0; j < 8; ++j) {
        int k = kt * 32 + quad * 8 + j;
        int col = k - ((L == 0) ? 0 : 400);
        float v = 0.f;
        if (prow < 30) {
          if (col >= 0 && col < 400) v = Ww[prow * 400 + col];
          else if (k == CONST_K)     v = bw[prow];
        }
        ushort_t h, l; split2(v, h, l);
        uh.s[j] = h; ul.s[j] = l;
      }
      apfh[pk] = uh.v; apfl[pk] = ul.v;
    }
  }

  // ---- one-time LDS init ----
  for (int i = tid; i < 16 * SBL; i += 256) { Bh[i] = 0; Bl[i] = 0; }
  for (int i = tid; i < 160; i += 256) skap[i / 10][i % 10] = 0.f;
  if constexpr (L <= 1) {
    for (int i = tid; i < 16 * 64; i += 256)
      sc[i >> 6][i & 63] = (unsigned char)c[(B0 + (i >> 6)) * U_ + (i & 63)];
  }
  __syncthreads();
  if (tid < 16) Bh[tid * SBL + CONST_K] = 0x3F80;  // bf16(1.0); lo stays 0
  __syncthreads();

  // ---- time loop (no pipeline padding; lag handled by progress waits) ----
  for (int t = 0; t < T_; ++t) {
    // -- cross-group waits (thread 0 polls; usually already satisfied) --
    if (tid == 0) {
      if constexpr (L == 0) {
        wait_ge(prog1, t - 3);                 // ring0 slot reuse
      } else if constexpr (L == 1) {
        wait_ge(prog0, t + 1);                 // h0(t) published
        wait_ge(prog2, t - 3);                 // ring1 + wring slot reuse
      } else {
        wait_ge(prog1, t + 1);                 // h1(t) + w(t) published
      }
    }
    __syncthreads();

    // -- staging: own h(t-1); L>=1 also h_prev(t); L2 also w(t); x(t) --
    stage_ring16(ringS + (size_t)((t + 3) & 3) * 12800 + B0 * 400, Bh, Bl, 0);
    if constexpr (L >= 1)
      stage_ring16(ringP + (size_t)(t & 3) * 12800 + B0 * 400, Bh, Bl, 400);
    if constexpr (L == 2) {
      const float* src = wring_c + (size_t)(t & 3) * 1920 + B0 * 60;
      for (int idx = tid; idx < 960; idx += 256) {
        int b = idx / 60, v = idx - b * 60;
        ushort_t h, l; split2(load_agent(src + idx), h, l);
        Bh[b * SBL + WOFF + v] = h; Bl[b * SBL + WOFF + v] = l;
      }
    }
    if (tid < 48) {
      int b = tid / 3, xc = tid - b * 3;
      ushort_t h, l;
      split2(x[((size_t)(B0 + b) * T_ + t) * 3 + xc], h, l);
      Bh[b * SBL + XOFF + xc] = h; Bl[b * SBL + XOFF + xc] = l;
    }
    __syncthreads();

    // -- attention (L0 computes w(t-1) for own input; L1 computes w(t)) --
    if constexpr (L <= 1) {
      const bool dow = (L == 1) || (t > 0);
      if (dow) {
        if (waveid < 2) {  // p-MFMA: rows waveid*16..+15 of 30, cols 16
          f32x4 acc = {0.f, 0.f, 0.f, 0.f};
          const int brow = l15 * SBL + quad * 8;
#pragma unroll
          for (int pk = 0; pk < 14; ++pk) {
            int kt = (pk < 13) ? ((L == 0) ? pk : 12 + pk) : ((L == 0) ? 14 : 26);
            bf16x8 bh8 = *(const bf16x8*)(Bh + brow + kt * 32);
            bf16x8 bl8 = *(const bf16x8*)(Bl + brow + kt * 32);
            acc = __builtin_amdgcn_mfma_f32_16x16x32_bf16(apfh[pk], bh8, acc, 0, 0, 0);
            acc = __builtin_amdgcn_mfma_f32_16x16x32_bf16(apfh[pk], bl8, acc, 0, 0, 0);
            acc = __builtin_amdgcn_mfma_f32_16x16x32_bf16(apfl[pk], bh8, acc, 0, 0, 0);
          }
#pragma unroll
          for (int r = 0; r < 4; ++r)
            sp[l15][waveid * 16 + quad * 4 + r] = acc[r];
        }
        __syncthreads();
        for (int idx = tid; idx < 480; idx += 256) {     // exp(p)
          int b = idx / 30, mm = idx - b * 30;
          sp[b][mm] = __expf(sp[b][mm]);
        }
        __syncthreads();
        for (int idx = tid; idx < 160; idx += 256) {     // kappa += dk
          int b = idx / 10, k2 = idx - b * 10;
          skap[b][k2] += sp[b][20 + k2];
        }
        __syncthreads();
        for (int idx = tid; idx < 1040; idx += 256) {    // phi
          int b = idx / 65, u = idx - b * 65;
          float s = 0.f;
#pragma unroll
          for (int k2 = 0; k2 < 10; ++k2) {
            float d = skap[b][k2] - (float)u;
            s = fmaf(sp[b][k2], __expf(-sp[b][10 + k2] * d * d), s);
          }
          su[b][u] = s;
        }
        __syncthreads();
        for (int idx = tid; idx < 960; idx += 256) {     // w gather
          int b = idx / 60, v = idx - b * 60;
          float s = 0.f;
#pragma unroll 8
          for (int u = 0; u < U_; ++u)
            s += (sc[b][u] == v) ? su[b][u] : 0.f;
          ushort_t h, l; split2(s, h, l);
          Bh[b * SBL + WOFF + v] = h; Bl[b * SBL + WOFF + v] = l;
          if (L == 1 && slice == 0)                      // publish w(t) for L2
            store_agent(wring_w + (size_t)(t & 3) * 1920 + B0 * 60 + idx, s);
        }
        if (L == 1 && t == T_ - 1 && slice == 0) {
          for (int idx = tid; idx < 1040; idx += 256)
            out_phi[(B0 + idx / 65) * 65 + (idx % 65)] = su[idx / 65][idx % 65];
        }
        __syncthreads();
      }
    }

    // -- main MFMA: rows = this wave's rowtile, cols = 16 samples --
    {
      f32x4 acc = {0.f, 0.f, 0.f, 0.f};
      const int brow = l15 * SBL + quad * 8;
#pragma unroll
      for (int kt = 0; kt < KT; ++kt) {
        bf16x8 bh8 = *(const bf16x8*)(Bh + brow + kt * 32);
        bf16x8 bl8 = *(const bf16x8*)(Bl + brow + kt * 32);
        acc = __builtin_amdgcn_mfma_f32_16x16x32_bf16(afh[kt], bh8, acc, 0, 0, 0);
        acc = __builtin_amdgcn_mfma_f32_16x16x32_bf16(afh[kt], bl8, acc, 0, 0, 0);
        acc = __builtin_amdgcn_mfma_f32_16x16x32_bf16(afl[kt], bh8, acc, 0, 0, 0);
      }
#pragma unroll
      for (int r = 0; r < 4; ++r)
        su[l15][rt * 16 + quad * 4 + r] = acc[r];   // su as sdots
    }
    __syncthreads();

    // -- combine: 256 threads = 16 samples x 16 units (unit fastest) --
    {
      int b = tid >> 4, u = tid & 15;
      int urt = u >> 2, u3 = u & 3;
      float rr = sigmoidf_(su[b][urt * 16 + 0 * 4 + u3]);
      float zz = sigmoidf_(su[b][urt * 16 + 1 * 4 + u3]);
      float hn = su[b][urt * 16 + 2 * 4 + u3];
      float inn = su[b][urt * 16 + 3 * 4 + u3];
      int Jc = slice * 16 + u;
      float hold = bfpair(Bh[b * SBL + Jc], Bl[b * SBL + Jc]);
      float hv = (1.f - zz) * tanhf(inn + rr * hn) + zz * hold;
      ushort_t hh, hl; split2(hv, hh, hl);
      store_agent_u32(ringS + (size_t)(t & 3) * 12800 + (B0 + b) * 400 + Jc,
                      ((unsigned)hh << 16) | (unsigned)hl);
      int n = (B0 + b) * T_ + t;
      size_t fo = (size_t)n * FEAT_LD + L * SEG + Jc;
      fh[fo] = hh; fl[fo] = hl;
    }

    // -- group barrier (drains all ring/wring stores), then publish progress
    group_barrier(gen);
    if (slice == 0 && tid == 0)
      store_agent_u32(progS, (unsigned)(t + 1));
  }
}

__global__ __launch_bounds__(256, 1)
void fused_scan(const float* __restrict__ x, const int* __restrict__ c,
                const float* Wih0, const float* Whh0, const float* bih0, const float* bhh0,
                const float* Wih1, const float* Whh1, const float* bih1, const float* bhh1,
                const float* Wih2, const float* Whh2, const float* bih2, const float* bhh2,
                const float* __restrict__ Ww, const float* __restrict__ bw,
                unsigned* ring0, unsigned* ring1, unsigned* ring2, float* wring,
                ushort_t* __restrict__ fh, ushort_t* __restrict__ fl,
                float* __restrict__ out_phi, unsigned* __restrict__ bar) {
  __shared__ ushort_t Bh[16 * SBL];
  __shared__ ushort_t Bl[16 * SBL];
  __shared__ float su[16][65];     // sdots (64 rows) UNION sphi (65)
  __shared__ float sp[16][33];     // attention p (exp'ed); rows 30,31 unused
  __shared__ float skap[16][10];
  __shared__ unsigned char sc[16][64];

  const int bx = blockIdx.x;
  const int grpL = bx / 50, r = bx % 50;
  const int slice = r >> 1, bhalf = r & 1;

  if (grpL == 0)
    scan_body<0>(slice, bhalf, x, c, Wih0, Whh0, bih0, bhh0, Ww, bw,
                 ring0, nullptr, nullptr, nullptr, fh, fl, out_phi, bar,
                 Bh, Bl, su, sp, skap, sc);
  else if (grpL == 1)
    scan_body<1>(slice, bhalf, x, c, Wih1, Whh1, bih1, bhh1, Ww, bw,
                 ring1, ring0, nullptr, wring, fh, fl, out_phi, bar,
                 Bh, Bl, su, sp, skap, sc);
  else
    scan_body<2>(slice, bhalf, x, c, Wih2, Whh2, bih2, bhh2, Ww, bw,
                 ring2, ring1, wring, nullptr, fh, fl, out_phi, bar,
                 Bh, Bl, su, sp, skap, sc);
}

// ---------------------------------------------------------------------------
__global__ __launch_bounds__(256)
void post_kernel(const float* __restrict__ p, float* __restrict__ dout) {
  int n = blockIdx.x * 256 + threadIdx.x;
  if (n >= N_) return;
  const float* r = p + (size_t)n * 128;
  dout[DO_LAST + n] = r[0];
  float mx = -1e30f;
  for (int m = 0; m < M_; ++m) mx = fmaxf(mx, r[1 + m]);
  float s = 0.f;
  for (int m = 0; m < M_; ++m) s += __expf(r[1 + m] - mx);
  float lse = mx + logf(s);
  for (int m = 0; m < M_; ++m) dout[DO_LOGW + (size_t)n * M_ + m] = r[1 + m] - lse;
  for (int i = 0; i < 2 * M_; ++i) dout[DO_MEANS + (size_t)n * 2 * M_ + i] = r[21 + i];
  for (int m = 0; m < M_; ++m) dout[DO_STD + (size_t)n * M_ + m] = __expf(r[61 + m]);
  for (int m = 0; m < M_; ++m) dout[DO_CORR + (size_t)n * M_ + m] = tanhf(r[81 + m]);
}

// ---------------------------------------------------------------------------
extern "C" void kernel_launch(void* const* d_in, const int* in_sizes, int n_in,
                              void* d_out, int out_size, void* d_ws, size_t ws_size,
                              hipStream_t stream) {
  const float* x    = (const float*)d_in[0];
  const int*   c    = (const int*)d_in[1];
  const float* Wih0 = (const float*)d_in[2];
  const float* Whh0 = (const float*)d_in[3];
  const float* bih0 = (const float*)d_in[4];
  const float* bhh0 = (const float*)d_in[5];
  const float* Wih1 = (const float*)d_in[6];
  const float* Whh1 = (const float*)d_in[7];
  const float* bih1 = (const float*)d_in[8];
  const float* bhh1 = (const float*)d_in[9];
  const float* Wih2 = (const float*)d_in[10];
  const float* Whh2 = (const float*)d_in[11];
  const float* bih2 = (const float*)d_in[12];
  const float* bhh2 = (const float*)d_in[13];
  const float* Ww   = (const float*)d_in[14];
  const float* bw   = (const float*)d_in[15];
  const float* Wh   = (const float*)d_in[16];
  const float* bh   = (const float*)d_in[17];
  (void)in_sizes; (void)n_in; (void)out_size; (void)ws_size;

  float* ws = (float*)d_ws;
  unsigned* ring0 = (unsigned*)(ws + OFF_R0);
  unsigned* ring1 = (unsigned*)(ws + OFF_R1);
  unsigned* ring2 = (unsigned*)(ws + OFF_R2);
  float*    wring = ws + OFF_WRING;
  unsigned* bar   = (unsigned*)(ws + OFF_BAR);
  ushort_t* fh    = (ushort_t*)(ws + OFF_FEATH);
  ushort_t* fl    = (ushort_t*)(ws + OFF_FEATL);
  ushort_t* whh_  = (ushort_t*)(ws + OFF_WHH);
  ushort_t* whl_  = (ushort_t*)(ws + OFF_WHL);
  float*    pbuf  = ws + OFF_P;
  float*    dout  = (float*)d_out;

  const dim3 blk(256);

  zero_ws<<<dim3((int)((ZERO_TOT + 255) / 256)), blk, 0, stream>>>(ws);
  zero_feat_pads<<<dim3((N_ * 48) / 256), blk, 0, stream>>>(fh, fl);
  split_wh_kernel<<<dim3((128 * FEAT_LD) / 256), blk, 0, stream>>>(Wh, whh_, whl_);

  fused_scan<<<dim3(NBLK), blk, 0, stream>>>(
      x, c, Wih0, Whh0, bih0, bhh0, Wih1, Whh1, bih1, bhh1,
      Wih2, Whh2, bih2, bhh2, Ww, bw,
      ring0, ring1, ring2, wring, fh, fl, dout + DO_PHI, bar);

  gemm_split_kernel<<<dim3(8 * (N_ / 16) / 4), blk, 0, stream>>>(
      whh_, whl_, fh, fl, bh, pbuf, 8, N_ / 16, FEAT_LD / 32,
      FEAT_LD, FEAT_LD, 121, 128);
  post_kernel<<<dim3(N_ / 256), blk, 0, stream>>>(pbuf, dout);
}

// Round 10
// 14533.325 us; speedup vs baseline: 1.0222x; 1.0222x over previous
//
#include <hip/hip_runtime.h>
#include <cmath>

// ---------------------------------------------------------------------------
// Graves handwriting synthesis: 3-layer GRU + attention window + MDN head
// B=32 T=512 U=64 V=60 H=400 K=10 M=20 IN=3
//
// Round 10: barrier-free dataflow sync.
//  - No group barriers, no master counters. Each block publishes ONE monotonic
//    flag per step (flag[group][slice] = t+1) after draining its stores.
//  - Step-start waits are WAVE-PARALLEL polls (one flag per lane + __all):
//      wave0: own group's 25 flags >= t     (peer h(t-1) ready, slot safety)
//      wave1: parent group    >= t+1        (h_prev(t), w(t) ready)   [L1,L2]
//      wave2: child group     >= t-3        (ring-slot reuse)         [L0,L1]
//    Hop chain per step: drain -> flag -> poll -> stage = 3 L3 RTTs, waits
//    overlapped. Wait graph acyclic + monotonic flags -> no deadlock.
//  Math / staging / fragments identical to r9 (passed, absmax 0.031).
// ---------------------------------------------------------------------------

typedef __attribute__((ext_vector_type(8))) short bf16x8;
typedef __attribute__((ext_vector_type(4))) float f32x4;
typedef unsigned short ushort_t;

namespace {
constexpr int B_ = 32, T_ = 512, U_ = 64, V_ = 60, H_ = 400, K_ = 10, M_ = 20;
constexpr int N_ = B_ * T_;          // 16384
constexpr int SEG = 416, FEAT_LD = 1248;
constexpr int NBLK = 150;
constexpr int SBL = 872;             // B-row stride in LDS (u16), 16B-aligned

// workspace layout (float indices)
constexpr size_t OFF_R0    = 0;                       // 4*32*400 u32 per ring
constexpr size_t OFF_R1    = 51200;
constexpr size_t OFF_R2    = 102400;
constexpr size_t OFF_WRING = 153600;                  // 4*32*60 f32
constexpr size_t OFF_BAR   = 161280;                  // 1088 uints
constexpr size_t ZERO_TOT  = OFF_BAR + 1088;
constexpr size_t OFF_FEATH = ZERO_TOT;                // N*1248 bf16
constexpr size_t OFF_FEATL = OFF_FEATH + (size_t)N_ * FEAT_LD / 2;
constexpr size_t OFF_WHH   = OFF_FEATL + (size_t)N_ * FEAT_LD / 2;  // 128*1248 bf16
constexpr size_t OFF_WHL   = OFF_WHH + (size_t)128 * FEAT_LD / 2;
constexpr size_t OFF_P     = OFF_WHL + (size_t)128 * FEAT_LD / 2;   // N*128 f32

// bar layout (uints): flags for group g (= L*2 + half) at [128 + 64*g + s],
// s = slice 0..24. 64-uint stride keeps each group on its own cache lines.
constexpr int BAR_FLAGS = 128;

// d_out layout (floats), reference return order
constexpr int DO_MEANS = 0;
constexpr int DO_STD   = B_ * T_ * M_ * 2;
constexpr int DO_LOGW  = DO_STD + B_ * T_ * M_;
constexpr int DO_CORR  = DO_LOGW + B_ * T_ * M_;
constexpr int DO_LAST  = DO_CORR + B_ * T_ * M_;
constexpr int DO_PHI   = DO_LAST + B_ * T_;
} // namespace

// ---------------------------------------------------------------------------
__device__ __forceinline__ float load_agent(const float* p) {
  return __hip_atomic_load(p, __ATOMIC_RELAXED, __HIP_MEMORY_SCOPE_AGENT);
}
__device__ __forceinline__ void store_agent(float* p, float v) {
  __hip_atomic_store(p, v, __ATOMIC_RELAXED, __HIP_MEMORY_SCOPE_AGENT);
}
__device__ __forceinline__ void store_agent_u32(unsigned* p, unsigned v) {
  __hip_atomic_store(p, v, __ATOMIC_RELAXED, __HIP_MEMORY_SCOPE_AGENT);
}
__device__ __forceinline__ unsigned load_agent_u32(const unsigned* p) {
  return __hip_atomic_load(p, __ATOMIC_RELAXED, __HIP_MEMORY_SCOPE_AGENT);
}
__device__ __forceinline__ unsigned long long load_agent_u64(const unsigned long long* p) {
  return __hip_atomic_load(p, __ATOMIC_RELAXED, __HIP_MEMORY_SCOPE_AGENT);
}
__device__ __forceinline__ ushort_t f2bf(float f) {
  union { float f; unsigned u; } x{f};
  unsigned r = x.u + 0x7FFFu + ((x.u >> 16) & 1u);
  return (ushort_t)(r >> 16);
}
__device__ __forceinline__ void split2(float f, ushort_t& h, ushort_t& l) {
  h = f2bf(f);
  union { unsigned u; float f; } c;
  c.u = ((unsigned)h) << 16;
  l = f2bf(f - c.f);
}
__device__ __forceinline__ float bfpair(ushort_t h, ushort_t l) {
  union { unsigned u; float f; } a, b;
  a.u = ((unsigned)h) << 16; b.u = ((unsigned)l) << 16;
  return a.f + b.f;
}
__device__ __forceinline__ float sigmoidf_(float x) {
  return 1.f / (1.f + __expf(-x));
}

// wave-parallel poll: lane i watches flags[i] (i<nf) until >= target.
__device__ __forceinline__ void wave_poll(const unsigned* flags, int nf, int target) {
  if (target <= 0) return;
  const int lane = threadIdx.x & 63;
  const unsigned* p = flags + (lane < nf ? lane : 0);
  for (;;) {
    int v = (int)load_agent_u32(p);
    if (__all(lane >= nf || v >= target)) break;
    __builtin_amdgcn_s_sleep(1);
  }
}

// stage one packed-ring 16x400 region into LDS split arrays (koff = col base)
__device__ __forceinline__ void stage_ring16(const unsigned* __restrict__ src,
                                             ushort_t* __restrict__ BhB,
                                             ushort_t* __restrict__ BlB, int koff) {
  for (int pi = threadIdx.x; pi < 3200; pi += 256) {   // 6400 elems / 2
    int e = pi * 2;
    int b = e / 400, k = e - b * 400;
    unsigned long long v = load_agent_u64((const unsigned long long*)(src + e));
    unsigned p0 = (unsigned)v, p1 = (unsigned)(v >> 32);
    unsigned hp = (p0 >> 16) | (p1 & 0xFFFF0000u);
    unsigned lp = (p0 & 0xFFFFu) | (p1 << 16);
    *(unsigned*)(BhB + b * SBL + koff + k) = hp;
    *(unsigned*)(BlB + b * SBL + koff + k) = lp;
  }
}

// ---------------------------------------------------------------------------
__global__ __launch_bounds__(256)
void zero_ws(float* __restrict__ p) {
  size_t i = (size_t)blockIdx.x * 256 + threadIdx.x;
  if (i < ZERO_TOT) p[i] = 0.f;
}

__global__ void zero_feat_pads(ushort_t* __restrict__ fh, ushort_t* __restrict__ fl) {
  int idx = blockIdx.x * 256 + threadIdx.x;
  if (idx >= N_ * 48) return;
  int n = idx / 48, r = idx % 48;
  size_t o = (size_t)n * FEAT_LD + (r / 16) * SEG + 400 + (r % 16);
  fh[o] = 0; fl[o] = 0;
}

__global__ void split_wh_kernel(const float* __restrict__ Wh,
                                ushort_t* __restrict__ hi, ushort_t* __restrict__ lo) {
  int idx = blockIdx.x * 256 + threadIdx.x;
  if (idx >= 128 * FEAT_LD) return;
  int m = idx / FEAT_LD, k = idx % FEAT_LD;
  int seg = k / SEG, off = k % SEG;
  float v = (m < 121 && off < 400) ? Wh[(size_t)m * 1200 + seg * 400 + off] : 0.f;
  ushort_t h, l; split2(v, h, l);
  hi[idx] = h; lo[idx] = l;
}

__global__ __launch_bounds__(256)
void gemm_split_kernel(const ushort_t* __restrict__ Ahi, const ushort_t* __restrict__ Alo,
                       const ushort_t* __restrict__ Bhi, const ushort_t* __restrict__ Blo,
                       const float* __restrict__ bias, float* __restrict__ C,
                       int mtiles, int ntiles, int ktiles, int strideA, int strideB,
                       int Mvalid, int ldc) {
  int wave = blockIdx.x * 4 + (threadIdx.x >> 6);
  if (wave >= mtiles * ntiles) return;
  int mt = wave / ntiles, nt = wave % ntiles;
  int lane = threadIdx.x & 63, l15 = lane & 15, quad = lane >> 4;
  size_t aoff = (size_t)(mt * 16 + l15) * strideA + quad * 8;
  size_t boff = (size_t)(nt * 16 + l15) * strideB + quad * 8;
  f32x4 acc = {0.f, 0.f, 0.f, 0.f};
  for (int kt = 0; kt < ktiles; ++kt) {
    bf16x8 ah = *(const bf16x8*)(Ahi + aoff + kt * 32);
    bf16x8 al = *(const bf16x8*)(Alo + aoff + kt * 32);
    bf16x8 bh = *(const bf16x8*)(Bhi + boff + kt * 32);
    bf16x8 bl = *(const bf16x8*)(Blo + boff + kt * 32);
    acc = __builtin_amdgcn_mfma_f32_16x16x32_bf16(ah, bh, acc, 0, 0, 0);
    acc = __builtin_amdgcn_mfma_f32_16x16x32_bf16(ah, bl, acc, 0, 0, 0);
    acc = __builtin_amdgcn_mfma_f32_16x16x32_bf16(al, bh, acc, 0, 0, 0);
  }
  int n = nt * 16 + l15;
#pragma unroll
  for (int r = 0; r < 4; ++r) {
    int m = mt * 16 + quad * 4 + r;
    if (m < Mvalid) C[(size_t)n * ldc + m] = acc[r] + bias[m];
  }
}

// ---------------------------------------------------------------------------
// fused pipelined scan body (templated per layer)
template <int L>
__device__ __forceinline__ void scan_body(
    int slice, int bhalf,
    const float* __restrict__ x, const int* __restrict__ c,
    const float* __restrict__ Wih, const float* __restrict__ Whh,
    const float* __restrict__ bih, const float* __restrict__ bhh,
    const float* __restrict__ Ww, const float* __restrict__ bw,
    unsigned* __restrict__ ringS, const unsigned* __restrict__ ringP,
    const float* __restrict__ wring_c, float* __restrict__ wring_w,
    ushort_t* __restrict__ fh, ushort_t* __restrict__ fl,
    float* __restrict__ out_phi, unsigned* __restrict__ bar,
    ushort_t* Bh, ushort_t* Bl, float (*su)[65], float (*sp)[33],
    float (*skap)[10], unsigned char (*sc)[64]) {
  constexpr int KT = (L == 0) ? 15 : 27;
  constexpr int CONST_K = (L == 0) ? 463 : 863;
  constexpr int XOFF = (L == 0) ? 460 : 860;
  constexpr int WOFF = (L == 0) ? 400 : 800;
  constexpr int IW = (L == 0) ? 63 : 463;
  const int tid = threadIdx.x;
  const int waveid = tid >> 6, lane = tid & 63;
  const int l15 = lane & 15, quad = lane >> 4;
  const int rt = waveid;                 // rowtile 0..3
  const int m = l15;
  const int uu = m & 3, gate = m >> 2;   // 0=r 1=z 2=hn 3=inn
  const int J = slice * 16 + rt * 4 + uu;
  const int B0 = bhalf * 16;             // first global sample of this block

  // flag plumbing: own / parent / child flag arrays
  unsigned* fOwn    = bar + BAR_FLAGS + 64 * (L * 2 + bhalf);
  unsigned* fParent = (L >= 1) ? bar + BAR_FLAGS + 64 * ((L - 1) * 2 + bhalf) : nullptr;
  unsigned* fChild  = (L <= 1) ? bar + BAR_FLAGS + 64 * ((L + 1) * 2 + bhalf) : nullptr;

  // ---- main A-fragments (split bf16), in registers for all 512 steps ----
  bf16x8 afh[KT], afl[KT];
#pragma unroll
  for (int kt = 0; kt < KT; ++kt) {
    union { bf16x8 v; ushort_t s[8]; } uh, ul;
#pragma unroll
    for (int j = 0; j < 8; ++j) {
      int k = kt * 32 + quad * 8 + j;
      float v = 0.f;
      if (k < 400) {
        if (gate == 0)      v = Whh[(size_t)J * 400 + k];
        else if (gate == 1) v = Whh[(size_t)(400 + J) * 400 + k];
        else if (gate == 2) v = Whh[(size_t)(800 + J) * 400 + k];
      } else if (k < CONST_K) {
        int col;
        if (L == 0) col = (k < 460) ? 3 + (k - 400) : (k - 460);
        else        col = (k < 800) ? 3 + (k - 400)
                        : (k < 860) ? 403 + (k - 800) : (k - 860);
        if (gate == 0)      v = Wih[(size_t)J * IW + col];
        else if (gate == 1) v = Wih[(size_t)(400 + J) * IW + col];
        else if (gate == 3) v = Wih[(size_t)(800 + J) * IW + col];
      } else if (k == CONST_K) {
        if (gate == 0)      v = bih[J] + bhh[J];
        else if (gate == 1) v = bih[400 + J] + bhh[400 + J];
        else if (gate == 2) v = bhh[800 + J];
        else                v = bih[800 + J];
      }
      ushort_t h, l; split2(v, h, l);
      uh.s[j] = h; ul.s[j] = l;
    }
    afh[kt] = uh.v; afl[kt] = ul.v;
  }

  // ---- attention p-fragments (Ww rows, split), L0/L1: waves 0/1 own 16 rows
  bf16x8 apfh[14], apfl[14];
  if constexpr (L <= 1) {
    const int prow = (waveid < 2) ? (waveid * 16 + l15) : 32;
#pragma unroll
    for (int pk = 0; pk < 14; ++pk) {
      int kt = (pk < 13) ? ((L == 0) ? pk : 12 + pk) : ((L == 0) ? 14 : 26);
      union { bf16x8 v; ushort_t s[8]; } uh, ul;
#pragma unroll
      for (int j = 0; j < 8; ++j) {
        int k = kt * 32 + quad * 8 + j;
        int col = k - ((L == 0) ? 0 : 400);
        float v = 0.f;
        if (prow < 30) {
          if (col >= 0 && col < 400) v = Ww[prow * 400 + col];
          else if (k == CONST_K)     v = bw[prow];
        }
        ushort_t h, l; split2(v, h, l);
        uh.s[j] = h; ul.s[j] = l;
      }
      apfh[pk] = uh.v; apfl[pk] = ul.v;
    }
  }

  // ---- one-time LDS init ----
  for (int i = tid; i < 16 * SBL; i += 256) { Bh[i] = 0; Bl[i] = 0; }
  for (int i = tid; i < 160; i += 256) skap[i / 10][i % 10] = 0.f;
  if constexpr (L <= 1) {
    for (int i = tid; i < 16 * 64; i += 256)
      sc[i >> 6][i & 63] = (unsigned char)c[(B0 + (i >> 6)) * U_ + (i & 63)];
  }
  __syncthreads();
  if (tid < 16) Bh[tid * SBL + CONST_K] = 0x3F80;  // bf16(1.0); lo stays 0
  __syncthreads();

  // ---- time loop: dataflow sync via wave-parallel flag polls ----
  for (int t = 0; t < T_; ++t) {
    if (waveid == 0)      wave_poll(fOwn, 25, t);             // peers done t-1
    else if (waveid == 1) { if (L >= 1) wave_poll(fParent, 25, t + 1); }
    else if (waveid == 2) { if (L <= 1) wave_poll(fChild, 25, t - 3); }
    __syncthreads();

    // -- staging: own h(t-1); L>=1 also h_prev(t); L2 also w(t); x(t) --
    stage_ring16(ringS + (size_t)((t + 3) & 3) * 12800 + B0 * 400, Bh, Bl, 0);
    if constexpr (L >= 1)
      stage_ring16(ringP + (size_t)(t & 3) * 12800 + B0 * 400, Bh, Bl, 400);
    if constexpr (L == 2) {
      const float* src = wring_c + (size_t)(t & 3) * 1920 + B0 * 60;
      for (int idx = tid; idx < 960; idx += 256) {
        int b = idx / 60, v = idx - b * 60;
        ushort_t h, l; split2(load_agent(src + idx), h, l);
        Bh[b * SBL + WOFF + v] = h; Bl[b * SBL + WOFF + v] = l;
      }
    }
    if (tid < 48) {
      int b = tid / 3, xc = tid - b * 3;
      ushort_t h, l;
      split2(x[((size_t)(B0 + b) * T_ + t) * 3 + xc], h, l);
      Bh[b * SBL + XOFF + xc] = h; Bl[b * SBL + XOFF + xc] = l;
    }
    __syncthreads();

    // -- attention (L0 computes w(t-1) for own input; L1 computes w(t)) --
    if constexpr (L <= 1) {
      const bool dow = (L == 1) || (t > 0);
      if (dow) {
        if (waveid < 2) {  // p-MFMA: rows waveid*16..+15 of 30, cols 16
          f32x4 acc = {0.f, 0.f, 0.f, 0.f};
          const int brow = l15 * SBL + quad * 8;
#pragma unroll
          for (int pk = 0; pk < 14; ++pk) {
            int kt = (pk < 13) ? ((L == 0) ? pk : 12 + pk) : ((L == 0) ? 14 : 26);
            bf16x8 bh8 = *(const bf16x8*)(Bh + brow + kt * 32);
            bf16x8 bl8 = *(const bf16x8*)(Bl + brow + kt * 32);
            acc = __builtin_amdgcn_mfma_f32_16x16x32_bf16(apfh[pk], bh8, acc, 0, 0, 0);
            acc = __builtin_amdgcn_mfma_f32_16x16x32_bf16(apfh[pk], bl8, acc, 0, 0, 0);
            acc = __builtin_amdgcn_mfma_f32_16x16x32_bf16(apfl[pk], bh8, acc, 0, 0, 0);
          }
#pragma unroll
          for (int r = 0; r < 4; ++r)
            sp[l15][waveid * 16 + quad * 4 + r] = acc[r];
        }
        __syncthreads();
        for (int idx = tid; idx < 480; idx += 256) {     // exp(p)
          int b = idx / 30, mm = idx - b * 30;
          sp[b][mm] = __expf(sp[b][mm]);
        }
        __syncthreads();
        for (int idx = tid; idx < 160; idx += 256) {     // kappa += dk
          int b = idx / 10, k2 = idx - b * 10;
          skap[b][k2] += sp[b][20 + k2];
        }
        __syncthreads();
        for (int idx = tid; idx < 1040; idx += 256) {    // phi
          int b = idx / 65, u = idx - b * 65;
          float s = 0.f;
#pragma unroll
          for (int k2 = 0; k2 < 10; ++k2) {
            float d = skap[b][k2] - (float)u;
            s = fmaf(sp[b][k2], __expf(-sp[b][10 + k2] * d * d), s);
          }
          su[b][u] = s;
        }
        __syncthreads();
        for (int idx = tid; idx < 960; idx += 256) {     // w gather
          int b = idx / 60, v = idx - b * 60;
          float s = 0.f;
#pragma unroll 8
          for (int u = 0; u < U_; ++u)
            s += (sc[b][u] == v) ? su[b][u] : 0.f;
          ushort_t h, l; split2(s, h, l);
          Bh[b * SBL + WOFF + v] = h; Bl[b * SBL + WOFF + v] = l;
          if (L == 1 && slice == 0)                      // publish w(t) for L2
            store_agent(wring_w + (size_t)(t & 3) * 1920 + B0 * 60 + idx, s);
        }
        if (L == 1 && t == T_ - 1 && slice == 0) {
          for (int idx = tid; idx < 1040; idx += 256)
            out_phi[(B0 + idx / 65) * 65 + (idx % 65)] = su[idx / 65][idx % 65];
        }
        __syncthreads();
      }
    }

    // -- main MFMA: rows = this wave's rowtile, cols = 16 samples --
    {
      f32x4 acc = {0.f, 0.f, 0.f, 0.f};
      const int brow = l15 * SBL + quad * 8;
#pragma unroll
      for (int kt = 0; kt < KT; ++kt) {
        bf16x8 bh8 = *(const bf16x8*)(Bh + brow + kt * 32);
        bf16x8 bl8 = *(const bf16x8*)(Bl + brow + kt * 32);
        acc = __builtin_amdgcn_mfma_f32_16x16x32_bf16(afh[kt], bh8, acc, 0, 0, 0);
        acc = __builtin_amdgcn_mfma_f32_16x16x32_bf16(afh[kt], bl8, acc, 0, 0, 0);
        acc = __builtin_amdgcn_mfma_f32_16x16x32_bf16(afl[kt], bh8, acc, 0, 0, 0);
      }
#pragma unroll
      for (int r = 0; r < 4; ++r)
        su[l15][rt * 16 + quad * 4 + r] = acc[r];   // su as sdots
    }
    __syncthreads();

    // -- combine: 256 threads = 16 samples x 16 units (unit fastest) --
    {
      int b = tid >> 4, u = tid & 15;
      int urt = u >> 2, u3 = u & 3;
      float rr = sigmoidf_(su[b][urt * 16 + 0 * 4 + u3]);
      float zz = sigmoidf_(su[b][urt * 16 + 1 * 4 + u3]);
      float hn = su[b][urt * 16 + 2 * 4 + u3];
      float inn = su[b][urt * 16 + 3 * 4 + u3];
      int Jc = slice * 16 + u;
      float hold = bfpair(Bh[b * SBL + Jc], Bl[b * SBL + Jc]);
      float hv = (1.f - zz) * tanhf(inn + rr * hn) + zz * hold;
      ushort_t hh, hl; split2(hv, hh, hl);
      store_agent_u32(ringS + (size_t)(t & 3) * 12800 + (B0 + b) * 400 + Jc,
                      ((unsigned)hh << 16) | (unsigned)hl);
      int n = (B0 + b) * T_ + t;
      size_t fo = (size_t)n * FEAT_LD + L * SEG + Jc;
      fh[fo] = hh; fl[fo] = hl;
    }

    // -- drain all stores, publish own flag (t+1) --
    __builtin_amdgcn_s_waitcnt(0);
    __syncthreads();
    if (tid == 0) store_agent_u32(fOwn + slice, (unsigned)(t + 1));
  }
}

__global__ __launch_bounds__(256, 1)
void fused_scan(const float* __restrict__ x, const int* __restrict__ c,
                const float* Wih0, const float* Whh0, const float* bih0, const float* bhh0,
                const float* Wih1, const float* Whh1, const float* bih1, const float* bhh1,
                const float* Wih2, const float* Whh2, const float* bih2, const float* bhh2,
                const float* __restrict__ Ww, const float* __restrict__ bw,
                unsigned* ring0, unsigned* ring1, unsigned* ring2, float* wring,
                ushort_t* __restrict__ fh, ushort_t* __restrict__ fl,
                float* __restrict__ out_phi, unsigned* __restrict__ bar) {
  __shared__ ushort_t Bh[16 * SBL];
  __shared__ ushort_t Bl[16 * SBL];
  __shared__ float su[16][65];     // sdots (64 rows) UNION sphi (65)
  __shared__ float sp[16][33];     // attention p (exp'ed); rows 30,31 unused
  __shared__ float skap[16][10];
  __shared__ unsigned char sc[16][64];

  const int bx = blockIdx.x;
  const int grpL = bx / 50, r = bx % 50;
  const int slice = r >> 1, bhalf = r & 1;

  if (grpL == 0)
    scan_body<0>(slice, bhalf, x, c, Wih0, Whh0, bih0, bhh0, Ww, bw,
                 ring0, nullptr, nullptr, nullptr, fh, fl, out_phi, bar,
                 Bh, Bl, su, sp, skap, sc);
  else if (grpL == 1)
    scan_body<1>(slice, bhalf, x, c, Wih1, Whh1, bih1, bhh1, Ww, bw,
                 ring1, ring0, nullptr, wring, fh, fl, out_phi, bar,
                 Bh, Bl, su, sp, skap, sc);
  else
    scan_body<2>(slice, bhalf, x, c, Wih2, Whh2, bih2, bhh2, Ww, bw,
                 ring2, ring1, wring, nullptr, fh, fl, out_phi, bar,
                 Bh, Bl, su, sp, skap, sc);
}

// ---------------------------------------------------------------------------
__global__ __launch_bounds__(256)
void post_kernel(const float* __restrict__ p, float* __restrict__ dout) {
  int n = blockIdx.x * 256 + threadIdx.x;
  if (n >= N_) return;
  const float* r = p + (size_t)n * 128;
  dout[DO_LAST + n] = r[0];
  float mx = -1e30f;
  for (int m = 0; m < M_; ++m) mx = fmaxf(mx, r[1 + m]);
  float s = 0.f;
  for (int m = 0; m < M_; ++m) s += __expf(r[1 + m] - mx);
  float lse = mx + logf(s);
  for (int m = 0; m < M_; ++m) dout[DO_LOGW + (size_t)n * M_ + m] = r[1 + m] - lse;
  for (int i = 0; i < 2 * M_; ++i) dout[DO_MEANS + (size_t)n * 2 * M_ + i] = r[21 + i];
  for (int m = 0; m < M_; ++m) dout[DO_STD + (size_t)n * M_ + m] = __expf(r[61 + m]);
  for (int m = 0; m < M_; ++m) dout[DO_CORR + (size_t)n * M_ + m] = tanhf(r[81 + m]);
}

// ---------------------------------------------------------------------------
extern "C" void kernel_launch(void* const* d_in, const int* in_sizes, int n_in,
                              void* d_out, int out_size, void* d_ws, size_t ws_size,
                              hipStream_t stream) {
  const float* x    = (const float*)d_in[0];
  const int*   c    = (const int*)d_in[1];
  const float* Wih0 = (const float*)d_in[2];
  const float* Whh0 = (const float*)d_in[3];
  const float* bih0 = (const float*)d_in[4];
  const float* bhh0 = (const float*)d_in[5];
  const float* Wih1 = (const float*)d_in[6];
  const float* Whh1 = (const float*)d_in[7];
  const float* bih1 = (const float*)d_in[8];
  const float* bhh1 = (const float*)d_in[9];
  const float* Wih2 = (const float*)d_in[10];
  const float* Whh2 = (const float*)d_in[11];
  const float* bih2 = (const float*)d_in[12];
  const float* bhh2 = (const float*)d_in[13];
  const float* Ww   = (const float*)d_in[14];
  const float* bw   = (const float*)d_in[15];
  const float* Wh   = (const float*)d_in[16];
  const float* bh   = (const float*)d_in[17];
  (void)in_sizes; (void)n_in; (void)out_size; (void)ws_size;

  float* ws = (float*)d_ws;
  unsigned* ring0 = (unsigned*)(ws + OFF_R0);
  unsigned* ring1 = (unsigned*)(ws + OFF_R1);
  unsigned* ring2 = (unsigned*)(ws + OFF_R2);
  float*    wring = ws + OFF_WRING;
  unsigned* bar   = (unsigned*)(ws + OFF_BAR);
  ushort_t* fh    = (ushort_t*)(ws + OFF_FEATH);
  ushort_t* fl    = (ushort_t*)(ws + OFF_FEATL);
  ushort_t* whh_  = (ushort_t*)(ws + OFF_WHH);
  ushort_t* whl_  = (ushort_t*)(ws + OFF_WHL);
  float*    pbuf  = ws + OFF_P;
  float*    dout  = (float*)d_out;

  const dim3 blk(256);

  zero_ws<<<dim3((int)((ZERO_TOT + 255) / 256)), blk, 0, stream>>>(ws);
  zero_feat_pads<<<dim3((N_ * 48) / 256), blk, 0, stream>>>(fh, fl);
  split_wh_kernel<<<dim3((128 * FEAT_LD) / 256), blk, 0, stream>>>(Wh, whh_, whl_);

  fused_scan<<<dim3(NBLK), blk, 0, stream>>>(
      x, c, Wih0, Whh0, bih0, bhh0, Wih1, Whh1, bih1, bhh1,
      Wih2, Whh2, bih2, bhh2, Ww, bw,
      ring0, ring1, ring2, wring, fh, fl, dout + DO_PHI, bar);

  gemm_split_kernel<<<dim3(8 * (N_ / 16) / 4), blk, 0, stream>>>(
      whh_, whl_, fh, fl, bh, pbuf, 8, N_ / 16, FEAT_LD / 32,
      FEAT_LD, FEAT_LD, 121, 128);
  post_kernel<<<dim3(N_ / 256), blk, 0, stream>>>(pbuf, dout);
}